// Round 4
// baseline (283.134 us; speedup 1.0000x reference)
//
#include <hip/hip_runtime.h>

#define NB 32
#define NP 512
#define NS 1024
#define NH 1024
#define NR 256
#define K3 3072

#define BM 64

typedef short short8 __attribute__((ext_vector_type(8)));
typedef __bf16 bf16x8 __attribute__((ext_vector_type(8)));
typedef float f32x4 __attribute__((ext_vector_type(4)));

__device__ __forceinline__ unsigned short f2bf(float f) {
  unsigned u = __builtin_bit_cast(unsigned, f);
  u += 0x7fffu + ((u >> 16) & 1u);   // round-to-nearest-even
  return (unsigned short)(u >> 16);
}

__device__ __forceinline__ f32x4 mfma_bf16(short8 a, short8 b, f32x4 c) {
  return __builtin_amdgcn_mfma_f32_16x16x32_bf16(
      __builtin_bit_cast(bf16x8, a), __builtin_bit_cast(bf16x8, b), c, 0, 0, 0);
}

// W fp32 [256][3072] -> FRAGMENT-MAJOR bf16 in ws:
//   WbF[kc][n16][lane] (short8), kc = k3/32 (96), n16 = n/16 (16), lane = lr+16*lg.
//   A wave's B-fragment load is one contiguous 1 KB burst (16 lines).
__global__ void wconv_kernel(const float* __restrict__ W,
                             unsigned short* __restrict__ WbF) {
  int i = blockIdx.x * blockDim.x + threadIdx.x;   // short8 id, 98304 total
  int lane = i & 63, n16 = (i >> 6) & 15, kc = i >> 10;
  int lr = lane & 15, lg = lane >> 4;
  const float* src = W + (size_t)(n16 * 16 + lr) * K3 + kc * 32 + lg * 8;
  float4 a = *(const float4*)src;
  float4 b = *(const float4*)(src + 4);
  short8 o;
  o[0] = (short)f2bf(a.x); o[1] = (short)f2bf(a.y);
  o[2] = (short)f2bf(a.z); o[3] = (short)f2bf(a.w);
  o[4] = (short)f2bf(b.x); o[5] = (short)f2bf(b.y);
  o[6] = (short)f2bf(b.z); o[7] = (short)f2bf(b.w);
  *(short8*)(WbF + (size_t)i * 8) = o;
}

// Fused gather + 3-part bf16 MFMA GEMM.
// R4: the R0-R3 arithmetic finally closes: per-stage cost is ~12k cycles of
// which only ~3k is MFMA+LDS; the rest is the barrier syncing all 8 waves on
// the SLOWEST of 128 random-row gathers whose prefetch slack was only one
// compute phase (~2.5k cyc) -- tail-latency-bound, 16x per block. Occupancy
// can't fix it (R3: 2nd block never co-resides; 21% either way). Fix: a
// 4-DEEP register ring for gathers (rA..rD, named arrays = compile-time
// indices, rule #20). store_stage(s) consumes gathers issued 4 stages ago
// (~10-12k cyc slack > tail), then refills the slot with gather(s+5).
// Queue per stage: W(s+1)[12] ... g(s+5)[8] -> store's wait is vmcnt(36),
// compute's wait on W is vmcnt(20): counted waits fit the 6-bit field, loads
// stay in flight across barriers (T4). launch_bounds(512,1) -> 256-VGPR cap
// for the ~212-reg ring (R1/R2 lesson: arg2 scales the cap; 2 forced 128).
// Store: one contiguous short8/array (thread owns cols 8q..8q+7), R2's
// 0-conflict shape; read swizzle unchanged.
__global__ __launch_bounds__(512, 1) void gemm_kernel(
    const int* __restrict__ pairs, const float* __restrict__ hs,
    const unsigned short* __restrict__ WbF, const float* __restrict__ bias,
    float* __restrict__ out) {
  __shared__ __align__(16) unsigned short sA[2][3][BM][64];  // 49152 B

  const int tid = threadIdx.x;
  const int blk = blockIdx.x;
  // XCD swizzle: blockIdx round-robins over 8 XCDs; give XCD x batches
  // 4x..4x+3 so a batch's 8 M-tiles share one XCD's L2 (R5: FETCH 122->63 MB).
  const int x     = blk & 7;
  const int jb    = blk >> 3;
  const int batch = x * 4 + (jb >> 3);
  const int mtile = jb & 7;
  const int m0    = (batch * 8 + mtile) * BM;

  // gather: 8 threads per pair; thread q covers float-cols 8q..8q+7
  // (two consecutive float4 per row per stage)
  const int pairi = tid >> 3;          // 0..63
  const int q     = tid & 7;
  int4 pr = ((const int4*)pairs)[m0 + pairi];
  const float* hb = hs + (size_t)batch * NS * NH + 8 * q;
  const float* rp[4];
  rp[0] = hb + (size_t)pr.x * NH;   // h_start
  rp[1] = hb + (size_t)pr.y * NH;   // h_end
  rp[2] = hb + (size_t)pr.z * NH;   // t_start
  rp[3] = hb + (size_t)pr.w * NH;   // t_end

  // MFMA lane mapping: 8 waves, wave w owns N-cols w*32..w*32+31
  const int lane = tid & 63;
  const int w    = tid >> 6;
  const int lr   = lane & 15;
  const int lg   = lane >> 4;

  // frag-major W: short addr = kc*8192 + n16*512 + lane*8; this wave: n16=2w+j
  const unsigned short* wbase = WbF + (size_t)(w * 2) * 512 + (size_t)lane * 8;

  f32x4 acc[4][2];
#pragma unroll
  for (int i = 0; i < 4; ++i)
#pragma unroll
    for (int j = 0; j < 2; ++j) acc[i][j] = (f32x4){0.f, 0.f, 0.f, 0.f};

  // gather ring, FOUR stages deep; slot d holds gathers for stage s with
  // s % 4 == d. ld[2r+h]: row r, float4-half h. 4 x 32 = 128 VGPRs.
  float4 rgA[8], rgB[8], rgC[8], rgD[8];
  short8 wcur[12], wnxt[12];    // W frags: idx = part*4 + ks*2 + j

  auto load_w = [&](int s, short8* wd) {
#pragma unroll
    for (int part = 0; part < 3; ++part)
#pragma unroll
      for (int ks = 0; ks < 2; ++ks)
#pragma unroll
        for (int j = 0; j < 2; ++j)
          wd[part * 4 + ks * 2 + j] = *(const short8*)(
              wbase + (size_t)(part * 32 + s * 2 + ks) * 8192 + (size_t)j * 512);
  };

  auto load_gather = [&](int s, float4* ld) {
    const int o = s * 64;
#pragma unroll
    for (int r = 0; r < 4; ++r) {
      ld[2 * r]     = *(const float4*)(rp[r] + o);
      ld[2 * r + 1] = *(const float4*)(rp[r] + o + 4);
    }
  };

  auto store_stage = [&](int buf, const float4* ld) {
    short8 hv, tv, pv;
#pragma unroll
    for (int e = 0; e < 8; ++e) {
      const int hi = e >> 2, ei = e & 3;
      float h = 0.5f * (((const float*)&ld[0 + hi])[ei] + ((const float*)&ld[2 + hi])[ei]);
      float t = 0.5f * (((const float*)&ld[4 + hi])[ei] + ((const float*)&ld[6 + hi])[ei]);
      float p = h * t;                 // product in fp32, rounded once
      hv[e] = (short)f2bf(h); tv[e] = (short)f2bf(t); pv[e] = (short)f2bf(p);
    }
    const int col = (q ^ (pairi & 7)) * 8;   // XOR swizzle, all 8 chunks/instr
    *(short8*)&sA[buf][0][pairi][col] = hv;
    *(short8*)&sA[buf][1][pairi][col] = tv;
    *(short8*)&sA[buf][2][pairi][col] = pv;
  };

  auto compute = [&](int buf, short8* wc) {
#pragma unroll
    for (int ks = 0; ks < 2; ++ks) {
      short8 ah[4], at4[4], ap[4];
      const int col = (((ks * 4 + lg) ^ (lr & 7)) * 8);            // XOR swizzle
#pragma unroll
      for (int i = 0; i < 4; ++i) {
        ah[i]  = *(const short8*)&sA[buf][0][i * 16 + lr][col];
        at4[i] = *(const short8*)&sA[buf][1][i * 16 + lr][col];
        ap[i]  = *(const short8*)&sA[buf][2][i * 16 + lr][col];
      }
#pragma unroll
      for (int j = 0; j < 2; ++j)
#pragma unroll
        for (int i = 0; i < 4; ++i) {
          acc[i][j] = mfma_bf16(ah[i],  wc[0 + ks * 2 + j], acc[i][j]);
          acc[i][j] = mfma_bf16(at4[i], wc[4 + ks * 2 + j], acc[i][j]);
          acc[i][j] = mfma_bf16(ap[i],  wc[8 + ks * 2 + j], acc[i][j]);
        }
    }
  };

  // prologue: W(0); fill the ring with gathers 0..3; stage-0 data to LDS;
  // refill slot A with gather(4) (consumed at stage 3).
  load_w(0, wcur);
  load_gather(0, rgA);
  load_gather(1, rgB);
  load_gather(2, rgC);
  load_gather(3, rgD);
  store_stage(0, rgA);                 // waits W0+g0 only (vmcnt(24))
  load_gather(4, rgA);

  // stage s: sync on buf[s&1]+wc; issue W(s+1); compute (regs+LDS only);
  // store gather(s+1) [issued ~4 stages ago] into buf[s&1^1]; refill the
  // consumed ring slot with gather(s+5).
  auto stage = [&](int s, short8* wc, short8* wn, float4* slot) {
    __syncthreads();
    if (s < 15) load_w(s + 1, wn);
    compute(s & 1, wc);
    if (s < 15) {
      store_stage((s & 1) ^ 1, slot);
      if (s <= 10) load_gather(s + 5, slot);
    }
  };

#pragma unroll 1
  for (int sp = 0; sp < 4; ++sp) {     // 4 stages/iter: W ping-pong x2, ring x1
    stage(4 * sp + 0, wcur, wnxt, rgB);
    stage(4 * sp + 1, wnxt, wcur, rgC);
    stage(4 * sp + 2, wcur, wnxt, rgD);
    stage(4 * sp + 3, wnxt, wcur, rgA);
  }

  // Epilogue: C/D layout row=(lane>>4)*4+reg, col=lane&15
#pragma unroll
  for (int j = 0; j < 2; ++j) {
    const int col  = w * 32 + j * 16 + lr;
    const float bv = bias[col];
#pragma unroll
    for (int i = 0; i < 4; ++i) {
      const size_t rbase = (size_t)(m0 + i * 16 + lg * 4) * NR + col;
#pragma unroll
      for (int r = 0; r < 4; ++r)
        out[rbase + (size_t)r * NR] = acc[i][j][r] + bv;
    }
  }
}

extern "C" void kernel_launch(void* const* d_in, const int* in_sizes, int n_in,
                              void* d_out, int out_size, void* d_ws, size_t ws_size,
                              hipStream_t stream) {
  const int*   pairs = (const int*)d_in[0];
  const float* hs    = (const float*)d_in[1];
  const float* W     = (const float*)d_in[2];
  const float* bias  = (const float*)d_in[3];
  float* out = (float*)d_out;
  unsigned short* WbF = (unsigned short*)d_ws;   // 1.5 MB frag-major bf16 W

  wconv_kernel<<<(96 * 16 * 64) / 256, 256, 0, stream>>>(W, WbF);
  gemm_kernel<<<(NB * NP) / BM, 512, 0, stream>>>(pairs, hs, WbF, bias, out);
}

// Round 5
// 230.222 us; speedup vs baseline: 1.2298x; 1.2298x over previous
//
#include <hip/hip_runtime.h>

#define NB 32
#define NP 512
#define NS 1024
#define NH 1024
#define NR 256
#define K3 3072

#define BM 64

typedef short short8 __attribute__((ext_vector_type(8)));
typedef __bf16 bf16x8 __attribute__((ext_vector_type(8)));
typedef float f32x4 __attribute__((ext_vector_type(4)));

__device__ __forceinline__ unsigned short f2bf(float f) {
  unsigned u = __builtin_bit_cast(unsigned, f);
  u += 0x7fffu + ((u >> 16) & 1u);   // round-to-nearest-even
  return (unsigned short)(u >> 16);
}

__device__ __forceinline__ f32x4 mfma_bf16(short8 a, short8 b, f32x4 c) {
  return __builtin_amdgcn_mfma_f32_16x16x32_bf16(
      __builtin_bit_cast(bf16x8, a), __builtin_bit_cast(bf16x8, b), c, 0, 0, 0);
}

// Raw workgroup barrier WITHOUT the vmem drain. __syncthreads() lowers to
// `s_waitcnt vmcnt(0) lgkmcnt(0); s_barrier` -- the vmcnt(0) drains the
// in-flight gather queue at EVERY stage, which is why no prefetch scheme
// helped in R0-R4 (the per-stage ~9k-cycle gather tail was structural).
// All cross-wave dependencies here are through LDS (ds_write -> ds_read),
// covered by lgkmcnt(0). Global loads are consumed by the issuing thread
// only; the compiler inserts its own COUNTED vmcnt waits at each use, so
// gathers genuinely stay in flight across barriers (T4).
__device__ __forceinline__ void wg_barrier() {
  asm volatile("s_waitcnt lgkmcnt(0)" ::: "memory");
  __builtin_amdgcn_s_barrier();
}

// W fp32 [256][3072] -> FRAGMENT-MAJOR bf16 in ws:
//   WbF[kc][n16][lane] (short8), kc = k3/32 (96), n16 = n/16 (16), lane = lr+16*lg.
//   A wave's B-fragment load is one contiguous 1 KB burst (16 lines).
__global__ void wconv_kernel(const float* __restrict__ W,
                             unsigned short* __restrict__ WbF) {
  int i = blockIdx.x * blockDim.x + threadIdx.x;   // short8 id, 98304 total
  int lane = i & 63, n16 = (i >> 6) & 15, kc = i >> 10;
  int lr = lane & 15, lg = lane >> 4;
  const float* src = W + (size_t)(n16 * 16 + lr) * K3 + kc * 32 + lg * 8;
  float4 a = *(const float4*)src;
  float4 b = *(const float4*)(src + 4);
  short8 o;
  o[0] = (short)f2bf(a.x); o[1] = (short)f2bf(a.y);
  o[2] = (short)f2bf(a.z); o[3] = (short)f2bf(a.w);
  o[4] = (short)f2bf(b.x); o[5] = (short)f2bf(b.y);
  o[6] = (short)f2bf(b.z); o[7] = (short)f2bf(b.w);
  *(short8*)(WbF + (size_t)i * 8) = o;
}

// Fused gather + 3-part bf16 MFMA GEMM.
// R5: R0's proven skeleton (BM=64, 512 thr, 12-frag W ping-pong one stage
// ahead, VGPR~116) + two changes:
//  (1) wg_barrier() instead of __syncthreads() -- no vmcnt(0) drain, loads
//      survive barriers (see comment above). This is the structural fix.
//  (2) gather prefetch distance 2 via ldA/ldB ping-pong (+32 VGPR, the only
//      depth that fits under the hard 128-VGPR cap proven in R4): gather(s+1)
//      is issued at stage s-1 and consumed at the END of stage s ->
//      ~2 compute phases + store + barrier of slack (~6k cyc) vs the ~2.5k
//      compute-only slack of R0.
// Queue order per stage: W(s+1) first, then g(s+2) -- compute(s)'s wait on
// W(s) is vmcnt(<=28) and never forces a younger gather to retire (in-order
// retire queue). store(s+1)'s wait on g(s+1) is vmcnt(<=20).
__global__ __launch_bounds__(512, 2) void gemm_kernel(
    const int* __restrict__ pairs, const float* __restrict__ hs,
    const unsigned short* __restrict__ WbF, const float* __restrict__ bias,
    float* __restrict__ out) {
  __shared__ __align__(16) unsigned short sA[2][3][BM][64];  // 49152 B

  const int tid = threadIdx.x;
  const int blk = blockIdx.x;
  // XCD swizzle: blockIdx round-robins over 8 XCDs; give XCD x batches
  // 4x..4x+3 so a batch's 8 M-tiles share one XCD's L2 (FETCH 122->63 MB).
  const int x     = blk & 7;
  const int jb    = blk >> 3;
  const int batch = x * 4 + (jb >> 3);
  const int mtile = jb & 7;
  const int m0    = (batch * 8 + mtile) * BM;

  // gather: 8 threads per pair; thread q covers float-cols 8q..8q+7
  // (two consecutive float4 per row per stage)
  const int pairi = tid >> 3;          // 0..63
  const int q     = tid & 7;
  int4 pr = ((const int4*)pairs)[m0 + pairi];
  const float* hb = hs + (size_t)batch * NS * NH + 8 * q;
  const float* rp[4];
  rp[0] = hb + (size_t)pr.x * NH;   // h_start
  rp[1] = hb + (size_t)pr.y * NH;   // h_end
  rp[2] = hb + (size_t)pr.z * NH;   // t_start
  rp[3] = hb + (size_t)pr.w * NH;   // t_end

  // MFMA lane mapping: 8 waves, wave w owns N-cols w*32..w*32+31
  const int lane = tid & 63;
  const int w    = tid >> 6;
  const int lr   = lane & 15;
  const int lg   = lane >> 4;

  // frag-major W: short addr = kc*8192 + n16*512 + lane*8; this wave: n16=2w+j
  const unsigned short* wbase = WbF + (size_t)(w * 2) * 512 + (size_t)lane * 8;

  f32x4 acc[4][2];
#pragma unroll
  for (int i = 0; i < 4; ++i)
#pragma unroll
    for (int j = 0; j < 2; ++j) acc[i][j] = (f32x4){0.f, 0.f, 0.f, 0.f};

  // gather prefetch, TWO stages deep (ping-pong). ld[2r+h]: row r, half h.
  float4 ldA[8], ldB[8];
  short8 wcur[12], wnxt[12];    // W frags: idx = part*4 + ks*2 + j

  auto load_w = [&](int s, short8* wd) {
#pragma unroll
    for (int part = 0; part < 3; ++part)
#pragma unroll
      for (int ks = 0; ks < 2; ++ks)
#pragma unroll
        for (int j = 0; j < 2; ++j)
          wd[part * 4 + ks * 2 + j] = *(const short8*)(
              wbase + (size_t)(part * 32 + s * 2 + ks) * 8192 + (size_t)j * 512);
  };

  auto load_gather = [&](int s, float4* ld) {
    const int o = s * 64;
#pragma unroll
    for (int r = 0; r < 4; ++r) {
      ld[2 * r]     = *(const float4*)(rp[r] + o);
      ld[2 * r + 1] = *(const float4*)(rp[r] + o + 4);
    }
  };

  auto store_stage = [&](int buf, const float4* ld) {
    short8 hv, tv, pv;
#pragma unroll
    for (int e = 0; e < 8; ++e) {
      const int hi = e >> 2, ei = e & 3;
      float h = 0.5f * (((const float*)&ld[0 + hi])[ei] + ((const float*)&ld[2 + hi])[ei]);
      float t = 0.5f * (((const float*)&ld[4 + hi])[ei] + ((const float*)&ld[6 + hi])[ei]);
      float p = h * t;                 // product in fp32, rounded once
      hv[e] = (short)f2bf(h); tv[e] = (short)f2bf(t); pv[e] = (short)f2bf(p);
    }
    const int col = (q ^ (pairi & 7)) * 8;   // XOR swizzle, all 8 chunks/instr
    *(short8*)&sA[buf][0][pairi][col] = hv;
    *(short8*)&sA[buf][1][pairi][col] = tv;
    *(short8*)&sA[buf][2][pairi][col] = pv;
  };

  auto compute = [&](int buf, short8* wc) {
#pragma unroll
    for (int ks = 0; ks < 2; ++ks) {
      short8 ah[4], at4[4], ap[4];
      const int col = (((ks * 4 + lg) ^ (lr & 7)) * 8);            // XOR swizzle
#pragma unroll
      for (int i = 0; i < 4; ++i) {
        ah[i]  = *(const short8*)&sA[buf][0][i * 16 + lr][col];
        at4[i] = *(const short8*)&sA[buf][1][i * 16 + lr][col];
        ap[i]  = *(const short8*)&sA[buf][2][i * 16 + lr][col];
      }
#pragma unroll
      for (int j = 0; j < 2; ++j)
#pragma unroll
        for (int i = 0; i < 4; ++i) {
          acc[i][j] = mfma_bf16(ah[i],  wc[0 + ks * 2 + j], acc[i][j]);
          acc[i][j] = mfma_bf16(at4[i], wc[4 + ks * 2 + j], acc[i][j]);
          acc[i][j] = mfma_bf16(ap[i],  wc[8 + ks * 2 + j], acc[i][j]);
        }
    }
  };

  // prologue: W(0) -> wcur; g(0) -> ldA; g(1) -> ldB; stage-0 tile to LDS.
  // (store waits g(0) only: vmcnt(8), g(1) stays outstanding.)
  load_w(0, wcur);
  load_gather(0, ldA);
  load_gather(1, ldB);
  store_stage(0, ldA);

  // stage s: barrier (lgkm only); issue W(s+1) then g(s+2) [into the slot
  // whose data was consumed at stage s-1]; compute(s); store g(s+1) [issued
  // at stage s-1, ~2 compute phases of slack] into buf[s&1^1].
  auto stage = [&](int s, short8* wc, short8* wn, float4* gin, float4* gout) {
    wg_barrier();
    if (s < 15) load_w(s + 1, wn);
    if (s < 14) load_gather(s + 2, gin);
    compute(s & 1, wc);
    if (s < 15) store_stage((s & 1) ^ 1, gout);
  };

#pragma unroll 1
  for (int sp = 0; sp < 8; ++sp) {     // W ping-pong; gather slot parity = s&1
    stage(2 * sp,     wcur, wnxt, ldA, ldB);
    stage(2 * sp + 1, wnxt, wcur, ldB, ldA);
  }

  // Epilogue: C/D layout row=(lane>>4)*4+reg, col=lane&15
#pragma unroll
  for (int j = 0; j < 2; ++j) {
    const int col  = w * 32 + j * 16 + lr;
    const float bv = bias[col];
#pragma unroll
    for (int i = 0; i < 4; ++i) {
      const size_t rbase = (size_t)(m0 + i * 16 + lg * 4) * NR + col;
#pragma unroll
      for (int r = 0; r < 4; ++r)
        out[rbase + (size_t)r * NR] = acc[i][j][r] + bv;
    }
  }
}

extern "C" void kernel_launch(void* const* d_in, const int* in_sizes, int n_in,
                              void* d_out, int out_size, void* d_ws, size_t ws_size,
                              hipStream_t stream) {
  const int*   pairs = (const int*)d_in[0];
  const float* hs    = (const float*)d_in[1];
  const float* W     = (const float*)d_in[2];
  const float* bias  = (const float*)d_in[3];
  float* out = (float*)d_out;
  unsigned short* WbF = (unsigned short*)d_ws;   // 1.5 MB frag-major bf16 W

  wconv_kernel<<<(96 * 16 * 64) / 256, 256, 0, stream>>>(W, WbF);
  gemm_kernel<<<(NB * NP) / BM, 512, 0, stream>>>(pairs, hs, WbF, bias, out);
}